// Round 7
// baseline (86.110 us; speedup 1.0000x reference)
//
#include <hip/hip_runtime.h>
#include <hip/hip_bf16.h>

#define BATCH 2048
#define NCLS  1000
#define FEAT  128
#define NBLK  512          // 32 row-tiles x 16 col-tiles of 64x64
#define LDS_STRIDE 136     // shorts/row: 128 + 8 pad -> 272 B rows (16B aligned,
                           // 4-way bank conflict on b128 reads = 1.58x, negligible)

typedef short  bf16x8 __attribute__((ext_vector_type(8)));
typedef short  short8 __attribute__((ext_vector_type(8)));
typedef float  f32x4  __attribute__((ext_vector_type(4)));
typedef float  f32x16 __attribute__((ext_vector_type(16)));

// ws layout: [0] uint completion counter (memset to 0 each launch);
//            [64..64+512) float likelihood partials (written every launch).
#define WS_LP 64

__device__ inline unsigned int pk2(float x, float y) {
    __hip_bfloat162 h = __float22bfloat162_rn(make_float2(x, y));  // RNE packed
    unsigned int u; __builtin_memcpy(&u, &h, 4); return u;
}

// Single fused kernel: 512 blocks x 256 threads (4 waves).
// Phase 1: stage fp32 A/B tiles -> LDS bf16, fp32 norm partials as by-product.
// Phase 2: 4 waves x 8 mfma_32x32x16_bf16 (2x2 grid of 32x32 tiles).
// Phase 3: epilogue stores + likelihood partial; last block reduces partials.
__global__ __launch_bounds__(256) void lgm_fused(
    const float* __restrict__ feat,
    const float* __restrict__ centers,
    const int* __restrict__ label,
    float* __restrict__ ws,
    float* __restrict__ out)
{
    __shared__ short As[64 * LDS_STRIDE];
    __shared__ short Bs[64 * LDS_STRIDE];
    __shared__ float fnp[1024];     // A norm partials, transposed: [seg*64 + row]
    __shared__ float cnp[1024];
    __shared__ float fn[64], cn[64];
    __shared__ int   lab[64];
    __shared__ float lkp[4];
    __shared__ float red[256];
    __shared__ int   isLast;

    int t       = threadIdx.x;
    int tileCol = blockIdx.x & 15;
    int tileRow = blockIdx.x >> 4;
    int rowBase = tileRow * 64;
    int colBase = tileCol * 64;

    // ---- Phase 1: stage tiles (fully coalesced: each wave reads 4 whole rows) ----
    #pragma unroll
    for (int j = 0; j < 4; j++) {
        int o  = j * 256 + t;        // octet index 0..1023 (8 elems each)
        int r  = o >> 4;             // tile-local row/col 0..63
        int cc = (o & 15) * 8;       // elem offset within the 128-elem row

        const float* pa = feat + (rowBase + r) * FEAT + cc;
        f32x4 a0 = *(const f32x4*)pa, a1 = *(const f32x4*)(pa + 4);
        fnp[(o & 15) * 64 + r] = a0[0]*a0[0] + a0[1]*a0[1] + a0[2]*a0[2] + a0[3]*a0[3]
                               + a1[0]*a1[0] + a1[1]*a1[1] + a1[2]*a1[2] + a1[3]*a1[3];
        union { unsigned int u[4]; short8 s; } pa8;
        pa8.u[0] = pk2(a0[0], a0[1]); pa8.u[1] = pk2(a0[2], a0[3]);
        pa8.u[2] = pk2(a1[0], a1[1]); pa8.u[3] = pk2(a1[2], a1[3]);
        *(short8*)(As + r * LDS_STRIDE + cc) = pa8.s;

        int gcol = colBase + r;
        gcol = (gcol < NCLS) ? gcol : (NCLS - 1);   // clamp; masked at store
        const float* pb = centers + gcol * FEAT + cc;
        f32x4 b0 = *(const f32x4*)pb, b1 = *(const f32x4*)(pb + 4);
        cnp[(o & 15) * 64 + r] = b0[0]*b0[0] + b0[1]*b0[1] + b0[2]*b0[2] + b0[3]*b0[3]
                               + b1[0]*b1[0] + b1[1]*b1[1] + b1[2]*b1[2] + b1[3]*b1[3];
        union { unsigned int u[4]; short8 s; } pb8;
        pb8.u[0] = pk2(b0[0], b0[1]); pb8.u[1] = pk2(b0[2], b0[3]);
        pb8.u[2] = pk2(b1[0], b1[1]); pb8.u[3] = pk2(b1[2], b1[3]);
        *(short8*)(Bs + r * LDS_STRIDE + cc) = pb8.s;
    }
    if (t < 64) lab[t] = label[rowBase + t];
    __syncthreads();
    if (t < 64) {
        float s0 = 0.f, s1 = 0.f;
        #pragma unroll
        for (int j = 0; j < 16; j++) { s0 += fnp[j * 64 + t]; s1 += cnp[j * 64 + t]; }
        fn[t] = s0; cn[t] = s1;      // exact fp32 norms (from fp32 inputs)
    }
    __syncthreads();

    // ---- Phase 2: MFMA ----
    int lane = t & 63, wave = t >> 6;
    int m    = lane & 31, half = lane >> 5;
    int rOff = (wave & 1) * 32;      // waves 0,2 -> rows 0..31; 1,3 -> 32..63
    int cOff = (wave >> 1) * 32;     // waves 0,1 -> cols 0..31; 2,3 -> 32..63
    const short* ap = As + (rOff + m) * LDS_STRIDE + half * 8;
    const short* bp = Bs + (cOff + m) * LDS_STRIDE + half * 8;

    f32x16 acc = {};
    #pragma unroll
    for (int kk = 0; kk < 8; kk++) {
        bf16x8 a = *(const bf16x8*)(ap + kk * 16);  // A[m][k=half*8+j]
        bf16x8 b = *(const bf16x8*)(bp + kk * 16);  // B^T[n][k=half*8+j]
        acc = __builtin_amdgcn_mfma_f32_32x32x16_bf16(a, b, acc, 0, 0, 0);
    }

    // ---- Phase 3: epilogue. C/D map: col=lane&31, row=(reg&3)+8*(reg>>2)+4*half ----
    float* out0 = out;
    float* out1 = out + BATCH * NCLS;
    int   c0    = colBase + cOff + m;
    bool  colOK = (c0 < NCLS);
    float cnv   = cn[cOff + m];
    float lk    = 0.f;
    #pragma unroll
    for (int reg = 0; reg < 16; reg++) {
        int rl    = rOff + (reg & 3) + 8 * (reg >> 2) + 4 * half;
        float dist  = fn[rl] + cnv - 2.0f * acc[reg];
        float logit = -0.5f * dist;
        if (colOK) {
            int idx = (rowBase + rl) * NCLS + c0;
            bool tru = (c0 == lab[rl]);
            out0[idx] = logit;
            out1[idx] = tru ? 2.0f * logit : logit;
            if (tru) lk += dist;     // exactly one (block,lane,reg) per row hits
        }
    }
    #pragma unroll
    for (int off = 32; off > 0; off >>= 1) lk += __shfl_down(lk, off, 64);
    if (lane == 0) lkp[wave] = lk;
    __syncthreads();

    if (t == 0) {
        float partial = lkp[0] + lkp[1] + lkp[2] + lkp[3];
        // device-scope atomics only (G16: no cross-XCD plain-load assumptions)
        atomicExch(&ws[WS_LP + blockIdx.x], partial);
        __threadfence();
        unsigned int old = atomicAdd((unsigned int*)ws, 1u);
        isLast = (old == NBLK - 1);
    }
    __syncthreads();

    if (isLast) {
        // deterministic: fixed-order reduction, independent of which block runs it
        float v = atomicAdd(&ws[WS_LP + 2 * t], 0.0f)
                + atomicAdd(&ws[WS_LP + 2 * t + 1], 0.0f);   // coherent reads
        red[t] = v;
        __syncthreads();
        if (t < 64) {
            float s = red[t] + red[t + 64] + red[t + 128] + red[t + 192];
            #pragma unroll
            for (int off = 32; off > 0; off >>= 1) s += __shfl_down(s, off, 64);
            if (t == 0) out[2 * BATCH * NCLS] = s * (0.5f / (float)BATCH);
        }
    }
}

extern "C" void kernel_launch(void* const* d_in, const int* in_sizes, int n_in,
                              void* d_out, int out_size, void* d_ws, size_t ws_size,
                              hipStream_t stream) {
    const float* feat    = (const float*)d_in[0];
    const int*   label   = (const int*)d_in[1];
    const float* centers = (const float*)d_in[2];
    float* ws = (float*)d_ws;

    hipMemsetAsync(d_ws, 0, 4, stream);   // completion counter = 0
    lgm_fused<<<NBLK, 256, 0, stream>>>(feat, centers, label, ws, (float*)d_out);
}

// Round 8
// 74.241 us; speedup vs baseline: 1.1599x; 1.1599x over previous
//
#include <hip/hip_runtime.h>
#include <hip/hip_bf16.h>

#define BATCH 2048
#define NCLS  1000
#define FEAT  128
#define NBLK  512          // 32 row-tiles x 16 col-tiles of 64x64
#define LDS_STRIDE 136     // shorts/row: 128 + 8 pad -> 272 B rows (16B aligned,
                           // 4-way bank conflict on b128 reads = 1.58x, negligible)

typedef short  bf16x8 __attribute__((ext_vector_type(8)));
typedef short  short8 __attribute__((ext_vector_type(8)));
typedef float  f32x4  __attribute__((ext_vector_type(4)));
typedef float  f32x16 __attribute__((ext_vector_type(16)));

// ws layout: [0] uint completion counter (memset to 0 each launch);
//            [64..64+512) float likelihood partials (written every launch).
#define WS_LP 64

__device__ inline unsigned int pk2(float x, float y) {
    __hip_bfloat162 h = __float22bfloat162_rn(make_float2(x, y));  // RNE packed
    unsigned int u; __builtin_memcpy(&u, &h, 4); return u;
}

// Single fused kernel: 512 blocks x 256 threads (4 waves).
// Phase 1: stage fp32 A/B tiles -> LDS bf16, fp32 norm partials as by-product.
// Phase 2: 4 waves x 8 mfma_32x32x16_bf16 (2x2 grid of 32x32 tiles).
// Phase 3: epilogue stores + likelihood partial; last block reduces partials.
// NO __threadfence (R7 post-mortem: device fence = per-block L2 writeback,
// +14.5us). Cross-block data moves ONLY via device-scope atomics (LLC-coherent,
// m20); ordering via returning-exch + s_waitcnt.
__global__ __launch_bounds__(256) void lgm_fused(
    const float* __restrict__ feat,
    const float* __restrict__ centers,
    const int* __restrict__ label,
    float* __restrict__ ws,
    float* __restrict__ out)
{
    __shared__ short As[64 * LDS_STRIDE];
    __shared__ short Bs[64 * LDS_STRIDE];
    __shared__ float fnp[1024];     // A norm partials, transposed: [seg*64 + row]
    __shared__ float cnp[1024];
    __shared__ float fn[64], cn[64];
    __shared__ int   lab[64];
    __shared__ float lkp[4];
    __shared__ float red[256];
    __shared__ int   isLast;

    int t       = threadIdx.x;
    int tileCol = blockIdx.x & 15;
    int tileRow = blockIdx.x >> 4;
    int rowBase = tileRow * 64;
    int colBase = tileCol * 64;

    // ---- Phase 1: stage tiles (fully coalesced: each wave reads 4 whole rows) ----
    #pragma unroll
    for (int j = 0; j < 4; j++) {
        int o  = j * 256 + t;        // octet index 0..1023 (8 elems each)
        int r  = o >> 4;             // tile-local row/col 0..63
        int cc = (o & 15) * 8;       // elem offset within the 128-elem row

        const float* pa = feat + (rowBase + r) * FEAT + cc;
        f32x4 a0 = *(const f32x4*)pa, a1 = *(const f32x4*)(pa + 4);
        fnp[(o & 15) * 64 + r] = a0[0]*a0[0] + a0[1]*a0[1] + a0[2]*a0[2] + a0[3]*a0[3]
                               + a1[0]*a1[0] + a1[1]*a1[1] + a1[2]*a1[2] + a1[3]*a1[3];
        union { unsigned int u[4]; short8 s; } pa8;
        pa8.u[0] = pk2(a0[0], a0[1]); pa8.u[1] = pk2(a0[2], a0[3]);
        pa8.u[2] = pk2(a1[0], a1[1]); pa8.u[3] = pk2(a1[2], a1[3]);
        *(short8*)(As + r * LDS_STRIDE + cc) = pa8.s;

        int gcol = colBase + r;
        gcol = (gcol < NCLS) ? gcol : (NCLS - 1);   // clamp; masked at store
        const float* pb = centers + gcol * FEAT + cc;
        f32x4 b0 = *(const f32x4*)pb, b1 = *(const f32x4*)(pb + 4);
        cnp[(o & 15) * 64 + r] = b0[0]*b0[0] + b0[1]*b0[1] + b0[2]*b0[2] + b0[3]*b0[3]
                               + b1[0]*b1[0] + b1[1]*b1[1] + b1[2]*b1[2] + b1[3]*b1[3];
        union { unsigned int u[4]; short8 s; } pb8;
        pb8.u[0] = pk2(b0[0], b0[1]); pb8.u[1] = pk2(b0[2], b0[3]);
        pb8.u[2] = pk2(b1[0], b1[1]); pb8.u[3] = pk2(b1[2], b1[3]);
        *(short8*)(Bs + r * LDS_STRIDE + cc) = pb8.s;
    }
    if (t < 64) lab[t] = label[rowBase + t];
    __syncthreads();
    if (t < 64) {
        float s0 = 0.f, s1 = 0.f;
        #pragma unroll
        for (int j = 0; j < 16; j++) { s0 += fnp[j * 64 + t]; s1 += cnp[j * 64 + t]; }
        fn[t] = s0; cn[t] = s1;      // exact fp32 norms (from fp32 inputs)
    }
    __syncthreads();

    // ---- Phase 2: MFMA ----
    int lane = t & 63, wave = t >> 6;
    int m    = lane & 31, half = lane >> 5;
    int rOff = (wave & 1) * 32;      // waves 0,2 -> rows 0..31; 1,3 -> 32..63
    int cOff = (wave >> 1) * 32;     // waves 0,1 -> cols 0..31; 2,3 -> 32..63
    const short* ap = As + (rOff + m) * LDS_STRIDE + half * 8;
    const short* bp = Bs + (cOff + m) * LDS_STRIDE + half * 8;

    f32x16 acc = {};
    #pragma unroll
    for (int kk = 0; kk < 8; kk++) {
        bf16x8 a = *(const bf16x8*)(ap + kk * 16);  // A[m][k=half*8+j]
        bf16x8 b = *(const bf16x8*)(bp + kk * 16);  // B^T[n][k=half*8+j]
        acc = __builtin_amdgcn_mfma_f32_32x32x16_bf16(a, b, acc, 0, 0, 0);
    }

    // ---- Phase 3: epilogue. C/D map: col=lane&31, row=(reg&3)+8*(reg>>2)+4*half ----
    float* out0 = out;
    float* out1 = out + BATCH * NCLS;
    int   c0    = colBase + cOff + m;
    bool  colOK = (c0 < NCLS);
    float cnv   = cn[cOff + m];
    float lk    = 0.f;
    #pragma unroll
    for (int reg = 0; reg < 16; reg++) {
        int rl    = rOff + (reg & 3) + 8 * (reg >> 2) + 4 * half;
        float dist  = fn[rl] + cnv - 2.0f * acc[reg];
        float logit = -0.5f * dist;
        if (colOK) {
            int idx = (rowBase + rl) * NCLS + c0;
            bool tru = (c0 == lab[rl]);
            out0[idx] = logit;
            out1[idx] = tru ? 2.0f * logit : logit;
            if (tru) lk += dist;     // exactly one (block,lane,reg) per row hits
        }
    }
    #pragma unroll
    for (int off = 32; off > 0; off >>= 1) lk += __shfl_down(lk, off, 64);
    if (lane == 0) lkp[wave] = lk;
    __syncthreads();

    if (t == 0) {
        float partial = lkp[0] + lkp[1] + lkp[2] + lkp[3];
        // Returning exch (sc0): vmcnt round-trip proves the partial is performed
        // at the LLC. Consume the old value so the returning form is emitted.
        float oldv = atomicExch(&ws[WS_LP + blockIdx.x], partial);
        if (__float_as_uint(oldv) == 0x13371337u)      // never true in practice;
            ws[WS_LP + blockIdx.x] = partial;          // harmless self-rewrite
        __builtin_amdgcn_s_waitcnt(0);                 // order: exch before counter
        unsigned int old = atomicAdd((unsigned int*)ws, 1u);
        isLast = (old == NBLK - 1);
    }
    __syncthreads();

    if (isLast) {
        // deterministic: fixed-order reduction, independent of which block runs it
        float v = atomicAdd(&ws[WS_LP + 2 * t], 0.0f)
                + atomicAdd(&ws[WS_LP + 2 * t + 1], 0.0f);   // LLC-coherent reads
        red[t] = v;
        __syncthreads();
        if (t < 64) {
            float s = red[t] + red[t + 64] + red[t + 128] + red[t + 192];
            #pragma unroll
            for (int off = 32; off > 0; off >>= 1) s += __shfl_down(s, off, 64);
            if (t == 0) out[2 * BATCH * NCLS] = s * (0.5f / (float)BATCH);
        }
    }
}

extern "C" void kernel_launch(void* const* d_in, const int* in_sizes, int n_in,
                              void* d_out, int out_size, void* d_ws, size_t ws_size,
                              hipStream_t stream) {
    const float* feat    = (const float*)d_in[0];
    const int*   label   = (const int*)d_in[1];
    const float* centers = (const float*)d_in[2];
    float* ws = (float*)d_ws;

    hipMemsetAsync(d_ws, 0, 4, stream);   // completion counter = 0
    lgm_fused<<<NBLK, 256, 0, stream>>>(feat, centers, label, ws, (float*)d_out);
}

// Round 9
// 72.727 us; speedup vs baseline: 1.1840x; 1.0208x over previous
//
#include <hip/hip_runtime.h>
#include <hip/hip_bf16.h>

#define BATCH 2048
#define NCLS  1000
#define FEAT  128

typedef short bf16x8 __attribute__((ext_vector_type(8)));
typedef float f32x16 __attribute__((ext_vector_type(16)));

// ws float-word layout (feat bf16 copy = 2048*128/2 = 131072 WORDS):
//   [0      .. 512)     likelihood block partials (one per prep feat-block)
//   [512    .. 2560)    fn[b] = |feat_b|^2
//   [2560   .. 3560)    cn[c] = |center_c|^2
//   [4096   .. 135168)  feat bf16 copy    (2048*128 bf16, packed 2/word)
//   [135168 .. 199168)  centers bf16 copy (1000*128 bf16, packed 2/word)
#define WS_LP   0
#define WS_FN   512
#define WS_CN   2560
#define WS_FB   4096
#define WS_CB   135168

__device__ inline unsigned int f2bf(float f) {
    unsigned int u;
    __builtin_memcpy(&u, &f, 4);
    return (u + 0x7fffu + ((u >> 16) & 1u)) >> 16;   // RNE
}

// One wave per row: w in [0,2048) = feat rows (|f|^2, likelihood partial, bf16
// copy), w in [2048,3048) = center rows (|c|^2, bf16 copy). Blocks 0..511 are
// pure feat blocks; each writes ONE likelihood partial. No atomics, no memset.
__global__ __launch_bounds__(256) void prep_kernel(
    const float* __restrict__ feat,
    const float* __restrict__ centers,
    const int* __restrict__ label,
    float* __restrict__ ws)
{
    __shared__ float lp[4];
    int w    = blockIdx.x * 4 + (threadIdx.x >> 6);
    int lane = threadIdx.x & 63;
    float* fn = ws + WS_FN;
    float* cn = ws + WS_CN;
    unsigned int* fb = (unsigned int*)(ws + WS_FB);
    unsigned int* cb = (unsigned int*)(ws + WS_CB);

    if (w < BATCH) {
        int b = w;
        float2 f = *(const float2*)(feat + b * FEAT + lane * 2);
        int lb = label[b];
        float2 c = *(const float2*)(centers + lb * FEAT + lane * 2);
        fb[b * 64 + lane] = f2bf(f.x) | (f2bf(f.y) << 16);
        float fs = f.x * f.x + f.y * f.y;
        float d0 = f.x - c.x, d1 = f.y - c.y;
        float ls = d0 * d0 + d1 * d1;
        #pragma unroll
        for (int off = 32; off > 0; off >>= 1) {
            fs += __shfl_down(fs, off, 64);
            ls += __shfl_down(ls, off, 64);
        }
        if (lane == 0) {
            fn[b] = fs;
            lp[threadIdx.x >> 6] = ls;
        }
    } else if (w < BATCH + NCLS) {
        int c = w - BATCH;
        float2 cv = *(const float2*)(centers + c * FEAT + lane * 2);
        cb[c * 64 + lane] = f2bf(cv.x) | (f2bf(cv.y) << 16);
        float cs = cv.x * cv.x + cv.y * cv.y;
        #pragma unroll
        for (int off = 32; off > 0; off >>= 1) cs += __shfl_down(cs, off, 64);
        if (lane == 0) cn[c] = cs;
    }

    if (blockIdx.x < 512) {            // block-uniform branch
        __syncthreads();
        if (threadIdx.x == 0)
            ws[WS_LP + blockIdx.x] = lp[0] + lp[1] + lp[2] + lp[3];
    }
}

// 256 threads = 4 waves in a 2x2 grid of 32x32 tiles -> 64x64 block tile.
// Each wave: 8 x mfma_f32_32x32x16_bf16 over K=128, pure bf16x8 loads from the
// L2-resident staging copies. Outputs stored NON-TEMPORAL (never re-read; keeps
// the staging copies from being evicted by the 16.4 MB write stream).
// Block 0 additionally reduces the 512 likelihood partials (kernel-boundary
// coherence: prep completed before this kernel starts).
__global__ __launch_bounds__(256) void lgm_main_kernel(
    const int* __restrict__ label,
    const float* __restrict__ ws,
    float* __restrict__ out)
{
    const float* fn = ws + WS_FN;
    const float* cn = ws + WS_CN;
    const unsigned short* fb = (const unsigned short*)(ws + WS_FB);
    const unsigned short* cb = (const unsigned short*)(ws + WS_CB);

    int tid     = threadIdx.x;
    int lane    = tid & 63;
    int wave    = tid >> 6;                 // 0..3
    int tileCol = blockIdx.x & 15;
    int tileRow = blockIdx.x >> 4;
    int rowBase = tileRow * 64 + (wave & 1) * 32;
    int colBase = tileCol * 64 + (wave >> 1) * 32;
    int m       = lane & 31;
    int half    = lane >> 5;                // 0..1

    int r  = rowBase + m;                   // A row for this lane
    int c0 = colBase + m;                   // output col for this lane
    int c  = (c0 < NCLS) ? c0 : (NCLS - 1); // clamped for loads

    const unsigned short* ap = fb + r * FEAT + half * 8;
    const unsigned short* bp = cb + c * FEAT + half * 8;

    f32x16 acc = {};
    #pragma unroll
    for (int kk = 0; kk < 8; kk++) {        // K=128 in steps of 16
        bf16x8 a = *(const bf16x8*)(ap + kk * 16); // A[m][k=half*8+j]
        bf16x8 b = *(const bf16x8*)(bp + kk * 16); // B^T[n][k=half*8+j]
        acc = __builtin_amdgcn_mfma_f32_32x32x16_bf16(a, b, acc, 0, 0, 0);
    }

    // C/D mapping (m74/m101): col = lane&31, row = (reg&3) + 8*(reg>>2) + 4*half
    float* out0 = out;                      // logits        [2048,1000]
    float* out1 = out + BATCH * NCLS;       // margin_logits [2048,1000]
    float cnv = cn[c];
    bool  colOK = (c0 < NCLS);
    #pragma unroll
    for (int reg = 0; reg < 16; reg++) {
        int row = rowBase + (reg & 3) + 8 * (reg >> 2) + 4 * half;
        if (colOK) {
            float dist  = fn[row] + cnv - 2.0f * acc[reg];
            float logit = -0.5f * dist;
            int idx = row * NCLS + c0;
            __builtin_nontemporal_store(logit, out0 + idx);
            __builtin_nontemporal_store((c0 == label[row]) ? 2.0f * logit : logit,
                                        out1 + idx);
        }
    }

    // Likelihood: sum the 512 prep partials (exactly 8 per lane), one wave.
    if (blockIdx.x == 0 && tid < 64) {
        float s = 0.0f;
        #pragma unroll
        for (int j = 0; j < 8; j++) s += ws[WS_LP + lane + 64 * j];
        #pragma unroll
        for (int off = 32; off > 0; off >>= 1) s += __shfl_down(s, off, 64);
        if (lane == 0) out[2 * BATCH * NCLS] = s * (0.5f / (float)BATCH);
    }
}

extern "C" void kernel_launch(void* const* d_in, const int* in_sizes, int n_in,
                              void* d_out, int out_size, void* d_ws, size_t ws_size,
                              hipStream_t stream) {
    const float* feat    = (const float*)d_in[0];
    const int*   label   = (const int*)d_in[1];
    const float* centers = (const float*)d_in[2];
    float* ws = (float*)d_ws;

    prep_kernel<<<762, 256, 0, stream>>>(feat, centers, label, ws);
    lgm_main_kernel<<<512, 256, 0, stream>>>(label, ws, (float*)d_out);
}